// Round 4
// baseline (1189.730 us; speedup 1.0000x reference)
//
#include <hip/hip_runtime.h>
#include <hip/hip_bf16.h>
#include <math.h>

// ---------- MoE dims (fixed by the problem) ----------
#define T_TOK 8192
#define DIM   1024
#define NEXP  8
#define TOPK  2
#define HID   4096
#define NSLOT (T_TOK * TOPK)
#define FLAG_GAP 1e-4f
#define MAXFLAG  2048
#define MBLK     136   // max live M-blocks: 16384/128 + 7 pad, rounded up

typedef unsigned short u16;
typedef __bf16 bf16x8 __attribute__((ext_vector_type(8)));
typedef float  f32x4  __attribute__((ext_vector_type(4)));
typedef u16    u16x4  __attribute__((ext_vector_type(4)));

// async global->LDS, 16B per lane; LDS dest is wave-uniform base + lane*16
#define GLL16(g, l) \
  __builtin_amdgcn_global_load_lds((__attribute__((address_space(1))) unsigned int*)(g), \
                                   (__attribute__((address_space(3))) unsigned int*)(l), 16, 0, 0)

__device__ __forceinline__ float bf2f(u16 u) {
  union { unsigned int i; float f; } w; w.i = ((unsigned int)u) << 16; return w.f;
}
__device__ __forceinline__ u16 f2bf(float f) {
  union { float f; unsigned int i; } w; w.f = f;
  unsigned int i = w.i;
  return (u16)((i + 0x7FFFu + ((i >> 16) & 1u)) >> 16);  // RNE
}
__device__ __forceinline__ float gelu_f(float v) {
  return 0.5f * v * (1.0f + erff(v * 0.70710678118654752f));
}

// ---------------------------------------------------------------------------
// fp32 -> (hi, lo) bf16 split: hi = bf16(v), lo = bf16(v - hi)
// ---------------------------------------------------------------------------
__global__ __launch_bounds__(256) void split_cast(
    const float* __restrict__ in, u16* __restrict__ hi, u16* __restrict__ lo, int n4)
{
  int i = blockIdx.x * 256 + threadIdx.x;
  if (i >= n4) return;
  f32x4 v = *(const f32x4*)&in[(size_t)i * 4];
  u16x4 h, l;
#pragma unroll
  for (int j = 0; j < 4; j++) {
    h[j] = f2bf(v[j]);
    l[j] = f2bf(v[j] - bf2f(h[j]));
  }
  *(u16x4*)&hi[(size_t)i * 4] = h;
  *(u16x4*)&lo[(size_t)i * 4] = l;
}

// ---------------------------------------------------------------------------
// fused cast+transpose: out_bf16[c][r] = in_f32[r][c]; per-expert blockIdx.z
// ---------------------------------------------------------------------------
__global__ __launch_bounds__(256) void transpose_cast(
    const float* __restrict__ in, u16* __restrict__ out, int R, int C)
{
  __shared__ u16 ld[64][65];
  const size_t mat = (size_t)R * C;
  const float* I = in + (size_t)blockIdx.z * mat;
  u16* O = out + (size_t)blockIdx.z * mat;
  const int c0 = blockIdx.x * 64, r0 = blockIdx.y * 64;
  const int tx = threadIdx.x & 15, ty = threadIdx.x >> 4;
#pragma unroll
  for (int p = 0; p < 4; p++) {
    int r = ty + p * 16;
    f32x4 v = *(const f32x4*)&I[(size_t)(r0 + r) * C + c0 + tx * 4];
    ld[r][tx * 4 + 0] = f2bf(v.x); ld[r][tx * 4 + 1] = f2bf(v.y);
    ld[r][tx * 4 + 2] = f2bf(v.z); ld[r][tx * 4 + 3] = f2bf(v.w);
  }
  __syncthreads();
#pragma unroll
  for (int p = 0; p < 4; p++) {
    int c = ty + p * 16;
    u16x4 v;
    v.x = ld[tx * 4 + 0][c]; v.y = ld[tx * 4 + 1][c];
    v.z = ld[tx * 4 + 2][c]; v.w = ld[tx * 4 + 3][c];
    *(u16x4*)&O[(size_t)(c0 + c) * R + r0 + tx * 4] = v;
  }
}

// transpose + hi/lo split (for Wr1): Ohi/Olo[c][r] = split(in[r][c])
__global__ __launch_bounds__(256) void transpose_cast_split(
    const float* __restrict__ in, u16* __restrict__ Ohi, u16* __restrict__ Olo,
    int R, int C)
{
  __shared__ float ld[64][65];
  const int c0 = blockIdx.x * 64, r0 = blockIdx.y * 64;
  const int tx = threadIdx.x & 15, ty = threadIdx.x >> 4;
#pragma unroll
  for (int p = 0; p < 4; p++) {
    int r = ty + p * 16;
    f32x4 v = *(const f32x4*)&in[(size_t)(r0 + r) * C + c0 + tx * 4];
    ld[r][tx * 4 + 0] = v.x; ld[r][tx * 4 + 1] = v.y;
    ld[r][tx * 4 + 2] = v.z; ld[r][tx * 4 + 3] = v.w;
  }
  __syncthreads();
#pragma unroll
  for (int p = 0; p < 4; p++) {
    int c = ty + p * 16;
    u16x4 h, l;
#pragma unroll
    for (int j = 0; j < 4; j++) {
      float v = ld[tx * 4 + j][c];
      h[j] = f2bf(v);
      l[j] = f2bf(v - bf2f(h[j]));
    }
    *(u16x4*)&Ohi[(size_t)(c0 + c) * R + r0 + tx * 4] = h;
    *(u16x4*)&Olo[(size_t)(c0 + c) * R + r0 + tx * 4] = l;
  }
}

// ---------------------------------------------------------------------------
// High-precision router GEMM1: hr = gelu( x @ Wr1 + br1 ), fp32 out.
// Split-bf16: acc = Ah*Bh + Ah*Bl + Al*Bh  (error ~2^-18, fp32-class).
// ---------------------------------------------------------------------------
__global__ __launch_bounds__(256) void gemm1_split(
    const u16* __restrict__ Ahi, const u16* __restrict__ Alo,
    const u16* __restrict__ Bhi, const u16* __restrict__ Blo,
    const float* __restrict__ bias, float* __restrict__ Cout)
{
  const int r0 = blockIdx.y * 128, n0 = blockIdx.x * 128;
  __shared__ __align__(16) u16 Ah[128 * 32], Al[128 * 32];
  __shared__ __align__(16) u16 Bh[128 * 32], Bl[128 * 32];

  const int tid = threadIdx.x;
  const int wave = tid >> 6, lane = tid & 63;
  const int srow = lane >> 2, scol = (lane & 3) * 8;

  const u16 *aph[2], *apl[2], *bph[2], *bpl[2];
  u16 *ahd[2], *ald[2], *bhd[2], *bld[2];
#pragma unroll
  for (int i = 0; i < 2; i++) {
    int r = wave * 32 + i * 16 + srow;
    size_t arow = (size_t)(r0 + r) * DIM + scol;
    size_t brow = (size_t)(n0 + r) * DIM + scol;
    aph[i] = Ahi + arow; apl[i] = Alo + arow;
    bph[i] = Bhi + brow; bpl[i] = Blo + brow;
    ahd[i] = &Ah[(wave * 32 + i * 16) * 32]; ald[i] = &Al[(wave * 32 + i * 16) * 32];
    bhd[i] = &Bh[(wave * 32 + i * 16) * 32]; bld[i] = &Bl[(wave * 32 + i * 16) * 32];
  }

  f32x4 zero = {0.f, 0.f, 0.f, 0.f};
  f32x4 acc[4][4];
#pragma unroll
  for (int a = 0; a < 4; a++)
#pragma unroll
    for (int b = 0; b < 4; b++) acc[a][b] = zero;

  const int quad = lane >> 4, l16 = lane & 15;
  const int wm = (wave & 1) * 64, wn = (wave >> 1) * 64;

  for (int k0 = 0; k0 < DIM; k0 += 32) {
#pragma unroll
    for (int i = 0; i < 2; i++) {
      GLL16(aph[i] + k0, ahd[i]);
      GLL16(apl[i] + k0, ald[i]);
      GLL16(bph[i] + k0, bhd[i]);
      GLL16(bpl[i] + k0, bld[i]);
    }
    __syncthreads();
    bf16x8 ah[4], al[4], bh[4], bl[4];
#pragma unroll
    for (int mt = 0; mt < 4; mt++) {
      int ro = (wm + mt * 16 + l16) * 32 + quad * 8;
      ah[mt] = *(const bf16x8*)&Ah[ro];
      al[mt] = *(const bf16x8*)&Al[ro];
    }
#pragma unroll
    for (int nt = 0; nt < 4; nt++) {
      int ro = (wn + nt * 16 + l16) * 32 + quad * 8;
      bh[nt] = *(const bf16x8*)&Bh[ro];
      bl[nt] = *(const bf16x8*)&Bl[ro];
    }
#pragma unroll
    for (int mt = 0; mt < 4; mt++)
#pragma unroll
      for (int nt = 0; nt < 4; nt++) {
        acc[mt][nt] = __builtin_amdgcn_mfma_f32_16x16x32_bf16(ah[mt], bh[nt], acc[mt][nt], 0, 0, 0);
        acc[mt][nt] = __builtin_amdgcn_mfma_f32_16x16x32_bf16(ah[mt], bl[nt], acc[mt][nt], 0, 0, 0);
        acc[mt][nt] = __builtin_amdgcn_mfma_f32_16x16x32_bf16(al[mt], bh[nt], acc[mt][nt], 0, 0, 0);
      }
    __syncthreads();
  }

  float bv[4];
#pragma unroll
  for (int nt = 0; nt < 4; nt++) bv[nt] = bias[n0 + wn + nt * 16 + l16];

#pragma unroll
  for (int mt = 0; mt < 4; mt++)
#pragma unroll
    for (int reg = 0; reg < 4; reg++) {
      int r = wm + mt * 16 + quad * 4 + reg;
      size_t crow = (size_t)(r0 + r) * DIM;
#pragma unroll
      for (int nt = 0; nt < 4; nt++) {
        int c = n0 + wn + nt * 16 + l16;
        Cout[crow + c] = gelu_f(acc[mt][nt][reg] + bv[nt]);
      }
    }
}

// ---------------------------------------------------------------------------
// Expert GEMM with compact block map: every blockIdx.y is a LIVE M-block.
// map_e[mb] = expert (or -1 pad), map_r0[mb] = row offset within expert.
// C[m,n] = epi( sum_k A[row(m),k] * BT[n,k] + bias[n] ), bf16 MFMA.
// EPI 0: bias+GELU -> bf16.  EPI 1: bias -> bf16.
// ---------------------------------------------------------------------------
template<int EPI, bool GATHER>
__global__ __launch_bounds__(256) void gemm_bt(
    const u16* __restrict__ A, const u16* __restrict__ BT,
    const float* __restrict__ bias,
    const int* __restrict__ counts, const int* __restrict__ offs,
    const int* __restrict__ map_e, const int* __restrict__ map_r0,
    const int* __restrict__ tok,
    u16* __restrict__ Cout, int N, int K)
{
  const int mb = blockIdx.y;
  const int e  = map_e[mb];
  if (e < 0) return;                                  // pad block
  const int cnt  = counts[e];
  const int r0   = map_r0[mb];
  const int base = offs[e];
  const int n0   = blockIdx.x * 128;
  const u16* BTe = BT + (size_t)e * N * K;
  const float* be = bias + (size_t)e * N;

  __shared__ __align__(16) u16 As[128 * 32];
  __shared__ __align__(16) u16 Bs[128 * 32];

  const int tid = threadIdx.x;
  const int wave = tid >> 6, lane = tid & 63;
  const int srow = lane >> 2, scol = (lane & 3) * 8;

  const u16* ap[2]; const u16* bp[2];
  u16* asd[2]; u16* bsd[2];
#pragma unroll
  for (int i = 0; i < 2; i++) {
    int r  = wave * 32 + i * 16 + srow;
    int rr = min(r0 + r, cnt - 1);                   // clamp tail (stores masked)
    int arow = GATHER ? tok[base + rr] : (base + rr);
    ap[i] = A + (size_t)arow * K + scol;
    int nr = n0 + wave * 32 + i * 16 + srow;
    bp[i] = BTe + (size_t)nr * K + scol;
    asd[i] = &As[(wave * 32 + i * 16) * 32];         // wave-uniform LDS base
    bsd[i] = &Bs[(wave * 32 + i * 16) * 32];
  }

  f32x4 zero = {0.f, 0.f, 0.f, 0.f};
  f32x4 acc[4][4];
#pragma unroll
  for (int a = 0; a < 4; a++)
#pragma unroll
    for (int b = 0; b < 4; b++) acc[a][b] = zero;

  const int quad = lane >> 4, l16 = lane & 15;
  const int wm = (wave & 1) * 64, wn = (wave >> 1) * 64;

  for (int k0 = 0; k0 < K; k0 += 32) {
#pragma unroll
    for (int i = 0; i < 2; i++) {
      GLL16(ap[i] + k0, asd[i]);
      GLL16(bp[i] + k0, bsd[i]);
    }
    __syncthreads();
    bf16x8 af[4], bfv[4];
#pragma unroll
    for (int mt = 0; mt < 4; mt++)
      af[mt] = *(const bf16x8*)&As[(wm + mt * 16 + l16) * 32 + quad * 8];
#pragma unroll
    for (int nt = 0; nt < 4; nt++)
      bfv[nt] = *(const bf16x8*)&Bs[(wn + nt * 16 + l16) * 32 + quad * 8];
#pragma unroll
    for (int mt = 0; mt < 4; mt++)
#pragma unroll
      for (int nt = 0; nt < 4; nt++)
        acc[mt][nt] = __builtin_amdgcn_mfma_f32_16x16x32_bf16(
            af[mt], bfv[nt], acc[mt][nt], 0, 0, 0);
    __syncthreads();
  }

  float bv[4];
#pragma unroll
  for (int nt = 0; nt < 4; nt++) bv[nt] = be[n0 + wn + nt * 16 + l16];

#pragma unroll
  for (int mt = 0; mt < 4; mt++)
#pragma unroll
    for (int reg = 0; reg < 4; reg++) {
      int r = wm + mt * 16 + quad * 4 + reg;         // C/D: row=quad*4+reg, col=lane&15
      if (r0 + r < cnt) {
        size_t crow = (size_t)(base + r0 + r) * N;
#pragma unroll
        for (int nt = 0; nt < 4; nt++) {
          int c = n0 + wn + nt * 16 + l16;
          float v = acc[mt][nt][reg] + bv[nt];
          Cout[crow + c] = f2bf(EPI == 0 ? gelu_f(v) : v);
        }
      }
    }
}

// ---------------------------------------------------------------------------
// Router stage 2a: logits = hr(fp32) @ Wr2 + br2; flag near-ties (2nd vs 3rd)
// ---------------------------------------------------------------------------
__global__ __launch_bounds__(256) void router2a(
    const float* __restrict__ hr, const float* __restrict__ Wr2,
    const float* __restrict__ br2,
    float* __restrict__ logits, int* __restrict__ nflag, int* __restrict__ flaglist)
{
  __shared__ float w[NEXP * DIM];
  __shared__ float bsh[NEXP];
  const int tid = threadIdx.x;
  for (int i = tid; i < NEXP * DIM; i += 256) {
    int d = i >> 3, e2 = i & 7;
    w[e2 * DIM + d] = Wr2[i];
  }
  if (tid < NEXP) bsh[tid] = br2[tid];
  __syncthreads();
  const int wave = tid >> 6, lane = tid & 63;
  for (int tt = 0; tt < 4; tt++) {
    int t = blockIdx.x * 16 + wave * 4 + tt;
    float acc[NEXP] = {0, 0, 0, 0, 0, 0, 0, 0};
    for (int jj = 0; jj < 16; jj++) {
      int d = jj * 64 + lane;
      float hv = hr[(size_t)t * DIM + d];
#pragma unroll
      for (int e2 = 0; e2 < NEXP; e2++) acc[e2] += hv * w[e2 * DIM + d];
    }
#pragma unroll
    for (int off = 32; off > 0; off >>= 1)
#pragma unroll
      for (int e2 = 0; e2 < NEXP; e2++) acc[e2] += __shfl_xor(acc[e2], off, 64);
    if (lane == 0) {
      float l[NEXP];
#pragma unroll
      for (int e2 = 0; e2 < NEXP; e2++) {
        l[e2] = acc[e2] + bsh[e2];
        logits[(size_t)t * NEXP + e2] = l[e2];
      }
      int e0 = 0;
#pragma unroll
      for (int e2 = 1; e2 < NEXP; e2++) if (l[e2] > l[e0]) e0 = e2;
      int e1 = (e0 == 0) ? 1 : 0;
#pragma unroll
      for (int e2 = 0; e2 < NEXP; e2++) if (e2 != e0 && l[e2] > l[e1]) e1 = e2;
      float third = -1e30f;
#pragma unroll
      for (int e2 = 0; e2 < NEXP; e2++)
        if (e2 != e0 && e2 != e1 && l[e2] > third) third = l[e2];
      if (l[e1] - third < FLAG_GAP) {
        int idx = atomicAdd(nflag, 1);
        if (idx < MAXFLAG) flaglist[idx] = t;
      }
    }
  }
}

// ---------------------------------------------------------------------------
// fp64 exact recompute of one flagged token's logits (from original fp32 in).
// ---------------------------------------------------------------------------
__global__ __launch_bounds__(256) void fixup_fp64(
    const float* __restrict__ x, const float* __restrict__ Wr1,
    const float* __restrict__ br1, const float* __restrict__ Wr2,
    const float* __restrict__ br2,
    const int* __restrict__ nflag, const int* __restrict__ flaglist,
    float* __restrict__ logits)
{
  int nf = *nflag; if (nf > MAXFLAG) nf = MAXFLAG;
  if ((int)blockIdx.x >= nf) return;
  const int t = flaglist[blockIdx.x];
  __shared__ float xs[DIM];
  __shared__ double part[256][NEXP];
  const int tid = threadIdx.x;
  for (int i = tid; i < DIM; i += 256) xs[i] = x[(size_t)t * DIM + i];
  __syncthreads();
  double h[4] = {0.0, 0.0, 0.0, 0.0};
  const int d0 = tid * 4;
  for (int k = 0; k < DIM; k++) {
    double xv = (double)xs[k];
    f32x4 wv = *(const f32x4*)&Wr1[(size_t)k * DIM + d0];
#pragma unroll
    for (int j = 0; j < 4; j++) h[j] = fma(xv, (double)wv[j], h[j]);
  }
  double lacc[NEXP] = {0, 0, 0, 0, 0, 0, 0, 0};
#pragma unroll
  for (int j = 0; j < 4; j++) {
    double v = h[j] + (double)br1[d0 + j];
    v = 0.5 * v * (1.0 + erf(v * 0.70710678118654752440));  // exact GELU
#pragma unroll
    for (int e2 = 0; e2 < NEXP; e2++)
      lacc[e2] = fma(v, (double)Wr2[(size_t)(d0 + j) * NEXP + e2], lacc[e2]);
  }
#pragma unroll
  for (int e2 = 0; e2 < NEXP; e2++) part[tid][e2] = lacc[e2];
  __syncthreads();
  if (tid < NEXP) {
    double s = (double)br2[tid];
    for (int i = 0; i < 256; i++) s += part[i][tid];
    logits[(size_t)t * NEXP + tid] = (float)s;
  }
}

// ---------------------------------------------------------------------------
// finalize: top-2 + renormalized gates + expert ids + per-expert counts
// ---------------------------------------------------------------------------
__global__ __launch_bounds__(256) void finalize_route(
    const float* __restrict__ logits, float2* __restrict__ gates,
    int* __restrict__ experts, int* __restrict__ counts)
{
  __shared__ int lc[NEXP];
  const int tid = threadIdx.x;
  if (tid < NEXP) lc[tid] = 0;
  __syncthreads();
  const int t = blockIdx.x * 256 + tid;
  float l[NEXP];
#pragma unroll
  for (int e2 = 0; e2 < NEXP; e2++) l[e2] = logits[(size_t)t * NEXP + e2];
  int e0 = 0;
#pragma unroll
  for (int e2 = 1; e2 < NEXP; e2++) if (l[e2] > l[e0]) e0 = e2;  // ties: low idx
  int e1 = (e0 == 0) ? 1 : 0;
#pragma unroll
  for (int e2 = 0; e2 < NEXP; e2++) if (e2 != e0 && l[e2] > l[e1]) e1 = e2;
  float p1 = expf(l[e1] - l[e0]);
  float s = 1.0f + p1;
  gates[t] = make_float2(1.0f / s, p1 / s);
  experts[2 * t]     = e0;
  experts[2 * t + 1] = e1;
  atomicAdd(&lc[e0], 1); atomicAdd(&lc[e1], 1);
  __syncthreads();
  if (tid < NEXP && lc[tid]) atomicAdd(&counts[tid], lc[tid]);
}

__global__ void zero_meta(int* meta) {
  if (threadIdx.x < 32) meta[threadIdx.x] = 0;
}

// offsets/cursors + compact live-block map (sum(counts)=NSLOT => <=135 blocks)
__global__ void prefix8(const int* __restrict__ counts, int* __restrict__ offs,
                        int* __restrict__ cursor,
                        int* __restrict__ map_e, int* __restrict__ map_r0) {
  if (threadIdx.x == 0) {
    int a = 0, m = 0;
    for (int e = 0; e < NEXP; e++) {
      offs[e] = a; cursor[e] = a;
      int nb = (counts[e] + 127) >> 7;
      for (int j = 0; j < nb; j++) { map_e[m] = e; map_r0[m] = j << 7; m++; }
      a += counts[e];
    }
    for (; m < MBLK; m++) { map_e[m] = -1; map_r0[m] = 0; }
  }
}

__global__ __launch_bounds__(256) void scatter_tok(
    const int* __restrict__ experts, int* __restrict__ cursor,
    int* __restrict__ tok_of_slot, int* __restrict__ slot_of_token)
{
  int idx = blockIdx.x * 256 + threadIdx.x;  // over NSLOT
  int e = experts[idx];
  int slot = atomicAdd(&cursor[e], 1);
  tok_of_slot[slot] = idx >> 1;
  slot_of_token[idx] = slot;
}

// out[t] = g0*y[slot0] + g1*y[slot1]  (y bf16; b2 added in layer-2 epilogue)
__global__ __launch_bounds__(256) void combine(
    const u16* __restrict__ y, const float2* __restrict__ gates,
    const int* __restrict__ slot_of_token, float* __restrict__ out)
{
  int t = blockIdx.x, tid = threadIdx.x;
  int s0 = slot_of_token[2 * t], s1 = slot_of_token[2 * t + 1];
  float2 g = gates[t];
  u16x4 a = *(const u16x4*)&y[(size_t)s0 * DIM + tid * 4];
  u16x4 b = *(const u16x4*)&y[(size_t)s1 * DIM + tid * 4];
  f32x4 o;
#pragma unroll
  for (int j = 0; j < 4; j++) o[j] = g.x * bf2f(a[j]) + g.y * bf2f(b[j]);
  *(f32x4*)&out[(size_t)t * DIM + tid * 4] = o;
}

// ---------------------------------------------------------------------------
extern "C" void kernel_launch(void* const* d_in, const int* in_sizes, int n_in,
                              void* d_out, int out_size, void* d_ws, size_t ws_size,
                              hipStream_t stream)
{
  const float* x   = (const float*)d_in[0];  // [T,D] fp32
  const float* Wr1 = (const float*)d_in[1];  // [D,D]
  const float* br1 = (const float*)d_in[2];  // [D]
  const float* Wr2 = (const float*)d_in[3];  // [D,E]
  const float* br2 = (const float*)d_in[4];  // [E]
  const float* W1  = (const float*)d_in[5];  // [E,D,H]
  const float* b1  = (const float*)d_in[6];  // [E,H]
  const float* W2  = (const float*)d_in[7];  // [E,H,D]
  const float* b2  = (const float*)d_in[8];  // [E,D]
  float* out = (float*)d_out;

  char* ws = (char*)d_ws;
  const size_t MB = 1024 * 1024;
  // explicit layout with lifetime-based aliasing (~294 MB total):
  u16*   xhi    = (u16*)  (ws + 0 * MB);     // [0,16)   dead after expert-L1
  u16*   xlo    = (u16*)  (ws + 16 * MB);    // [16,32)  dead after gemm1
  u16*   Wr1Thi = (u16*)  (ws + 32 * MB);    // [32,34)  dead after gemm1
  u16*   Wr1Tlo = (u16*)  (ws + 34 * MB);    // [34,36)  dead after gemm1
  u16*   W1T    = (u16*)  (ws + 36 * MB);    // [36,100) dead after expert-L1
  u16*   W2T    = (u16*)  (ws + 100 * MB);   // [100,164) live until L2
  u16*   hidden = (u16*)  (ws + 164 * MB);   // [164,292) bf16
  float* hr32   = (float*)(ws + 164 * MB);   // alias: dead before L1 writes hidden
  u16*   y      = (u16*)  (ws + 0 * MB);     // [0,32) bf16: written by L2, after
                                             //   xhi/xlo are dead
  char* tail = ws + 292 * MB;
  float*  logits = (float*)tail;                      tail += (size_t)T_TOK * NEXP * 4;
  float2* gates  = (float2*)tail;                     tail += (size_t)T_TOK * 8;
  int* experts       = (int*)tail;                    tail += (size_t)NSLOT * 4;
  int* tok_of_slot   = (int*)tail;                    tail += (size_t)NSLOT * 4;
  int* slot_of_token = (int*)tail;                    tail += (size_t)NSLOT * 4;
  int* flaglist      = (int*)tail;                    tail += (size_t)MAXFLAG * 4;
  int* map_e         = (int*)tail;                    tail += (size_t)MBLK * 4;
  int* map_r0        = (int*)tail;                    tail += (size_t)MBLK * 4;
  int* meta          = (int*)tail;  // counts[8] | offs[8] | cursor[8] | nflag
  int* counts = meta, *offs = meta + 8, *cursor = meta + 16, *nflag = meta + 24;

  zero_meta<<<1, 64, 0, stream>>>(meta);
  // ingest: x -> bf16 hi/lo split; weights -> bf16 B^T (Wr1 also split)
  split_cast<<<T_TOK * DIM / 1024, 256, 0, stream>>>(x, xhi, xlo, T_TOK * DIM / 4);
  transpose_cast_split<<<dim3(16, 16, 1), 256, 0, stream>>>(Wr1, Wr1Thi, Wr1Tlo, DIM, DIM);
  transpose_cast<<<dim3(64, 16, NEXP), 256, 0, stream>>>(W1, W1T, DIM, HID);
  transpose_cast<<<dim3(16, 64, NEXP), 256, 0, stream>>>(W2, W2T, HID, DIM);
  // router layer 1, fp32-class precision via 3-product split-bf16 MFMA
  gemm1_split<<<dim3(DIM / 128, T_TOK / 128), 256, 0, stream>>>(
      xhi, xlo, Wr1Thi, Wr1Tlo, br1, hr32);
  // fp32 logits + near-tie flags; fp64 fixup; final top-2 + gates + counts
  router2a<<<T_TOK / 16, 256, 0, stream>>>(hr32, Wr2, br2, logits, nflag, flaglist);
  fixup_fp64<<<MAXFLAG, 256, 0, stream>>>(x, Wr1, br1, Wr2, br2, nflag, flaglist, logits);
  finalize_route<<<T_TOK / 256, 256, 0, stream>>>(logits, gates, experts, counts);
  prefix8<<<1, 64, 0, stream>>>(counts, offs, cursor, map_e, map_r0);
  scatter_tok<<<NSLOT / 256, 256, 0, stream>>>(experts, cursor,
                                               tok_of_slot, slot_of_token);
  // expert layer 1 (gather x rows): hidden = gelu(xg @ W1[e] + b1[e]) bf16
  gemm_bt<0, true><<<dim3(HID / 128, MBLK), 256, 0, stream>>>(
      xhi, W1T, b1, counts, offs, map_e, map_r0, tok_of_slot, hidden, HID, DIM);
  // expert layer 2: y = hidden @ W2[e] + b2[e], bf16
  gemm_bt<1, false><<<dim3(DIM / 128, MBLK), 256, 0, stream>>>(
      hidden, W2T, b2, counts, offs, map_e, map_r0, nullptr, y, DIM, HID);
  // weighted combine -> fp32 out
  combine<<<T_TOK, 256, 0, stream>>>(y, gates, slot_of_token, out);
}

// Round 5
// 987.455 us; speedup vs baseline: 1.2048x; 1.2048x over previous
//
#include <hip/hip_runtime.h>
#include <hip/hip_bf16.h>
#include <math.h>

// ---------- MoE dims (fixed by the problem) ----------
#define T_TOK 8192
#define DIM   1024
#define NEXP  8
#define TOPK  2
#define HID   4096
#define NSLOT (T_TOK * TOPK)
#define FLAG_GAP 1e-4f
#define MAXFLAG  2048
#define MBLK     136   // max live M-blocks: 16384/128 + 7 pad, rounded up

typedef unsigned short u16;
typedef __bf16 bf16x8 __attribute__((ext_vector_type(8)));
typedef float  f32x4  __attribute__((ext_vector_type(4)));
typedef u16    u16x4  __attribute__((ext_vector_type(4)));

// async global->LDS, 16B per lane; LDS dest is wave-uniform base + lane*16
#define GLL16(g, l) \
  __builtin_amdgcn_global_load_lds((__attribute__((address_space(1))) unsigned int*)(g), \
                                   (__attribute__((address_space(3))) unsigned int*)(l), 16, 0, 0)

__device__ __forceinline__ float bf2f(u16 u) {
  union { unsigned int i; float f; } w; w.i = ((unsigned int)u) << 16; return w.f;
}
__device__ __forceinline__ u16 f2bf(float f) {
  union { float f; unsigned int i; } w; w.f = f;
  unsigned int i = w.i;
  return (u16)((i + 0x7FFFu + ((i >> 16) & 1u)) >> 16);  // RNE
}
// Abramowitz-Stegun 7.1.26 erf, |err| <= ~3e-7 (incl. rcp) — plenty for bf16 path
__device__ __forceinline__ float erf_fast(float x) {
  float ax = fabsf(x);
  float t = __builtin_amdgcn_rcpf(1.0f + 0.3275911f * ax);
  float p = t * (0.254829592f + t * (-0.284496736f + t * (1.421413741f +
            t * (-1.453152027f + t * 1.061405429f))));
  float e = __expf(-ax * ax);
  float r = 1.0f - p * e;
  return x < 0.0f ? -r : r;
}
__device__ __forceinline__ float gelu_fast(float v) {
  return 0.5f * v * (1.0f + erf_fast(v * 0.70710678118654752f));
}

// ---------------------------------------------------------------------------
// fp32 -> (hi, lo) bf16 split: hi = bf16(v), lo = bf16(v - hi)
// ---------------------------------------------------------------------------
__global__ __launch_bounds__(256) void split_cast(
    const float* __restrict__ in, u16* __restrict__ hi, u16* __restrict__ lo, int n4)
{
  int i = blockIdx.x * 256 + threadIdx.x;
  if (i >= n4) return;
  f32x4 v = *(const f32x4*)&in[(size_t)i * 4];
  u16x4 h, l;
#pragma unroll
  for (int j = 0; j < 4; j++) {
    h[j] = f2bf(v[j]);
    l[j] = f2bf(v[j] - bf2f(h[j]));
  }
  *(u16x4*)&hi[(size_t)i * 4] = h;
  *(u16x4*)&lo[(size_t)i * 4] = l;
}

// ---------------------------------------------------------------------------
// fused cast+transpose: out_bf16[c][r] = in_f32[r][c]; per-expert blockIdx.z
// ---------------------------------------------------------------------------
__global__ __launch_bounds__(256) void transpose_cast(
    const float* __restrict__ in, u16* __restrict__ out, int R, int C)
{
  __shared__ u16 ld[64][65];
  const size_t mat = (size_t)R * C;
  const float* I = in + (size_t)blockIdx.z * mat;
  u16* O = out + (size_t)blockIdx.z * mat;
  const int c0 = blockIdx.x * 64, r0 = blockIdx.y * 64;
  const int tx = threadIdx.x & 15, ty = threadIdx.x >> 4;
#pragma unroll
  for (int p = 0; p < 4; p++) {
    int r = ty + p * 16;
    f32x4 v = *(const f32x4*)&I[(size_t)(r0 + r) * C + c0 + tx * 4];
    ld[r][tx * 4 + 0] = f2bf(v.x); ld[r][tx * 4 + 1] = f2bf(v.y);
    ld[r][tx * 4 + 2] = f2bf(v.z); ld[r][tx * 4 + 3] = f2bf(v.w);
  }
  __syncthreads();
#pragma unroll
  for (int p = 0; p < 4; p++) {
    int c = ty + p * 16;
    u16x4 v;
    v.x = ld[tx * 4 + 0][c]; v.y = ld[tx * 4 + 1][c];
    v.z = ld[tx * 4 + 2][c]; v.w = ld[tx * 4 + 3][c];
    *(u16x4*)&O[(size_t)(c0 + c) * R + r0 + tx * 4] = v;
  }
}

// transpose + hi/lo split (for Wr1): Ohi/Olo[c][r] = split(in[r][c])
__global__ __launch_bounds__(256) void transpose_cast_split(
    const float* __restrict__ in, u16* __restrict__ Ohi, u16* __restrict__ Olo,
    int R, int C)
{
  __shared__ float ld[64][65];
  const int c0 = blockIdx.x * 64, r0 = blockIdx.y * 64;
  const int tx = threadIdx.x & 15, ty = threadIdx.x >> 4;
#pragma unroll
  for (int p = 0; p < 4; p++) {
    int r = ty + p * 16;
    f32x4 v = *(const f32x4*)&in[(size_t)(r0 + r) * C + c0 + tx * 4];
    ld[r][tx * 4 + 0] = v.x; ld[r][tx * 4 + 1] = v.y;
    ld[r][tx * 4 + 2] = v.z; ld[r][tx * 4 + 3] = v.w;
  }
  __syncthreads();
#pragma unroll
  for (int p = 0; p < 4; p++) {
    int c = ty + p * 16;
    u16x4 h, l;
#pragma unroll
    for (int j = 0; j < 4; j++) {
      float v = ld[tx * 4 + j][c];
      h[j] = f2bf(v);
      l[j] = f2bf(v - bf2f(h[j]));
    }
    *(u16x4*)&Ohi[(size_t)(c0 + c) * R + r0 + tx * 4] = h;
    *(u16x4*)&Olo[(size_t)(c0 + c) * R + r0 + tx * 4] = l;
  }
}

// ---------------------------------------------------------------------------
// High-precision router GEMM1: hr = gelu( x @ Wr1 + br1 ), fp32 out.
// Split-bf16, 3 MFMA products. Tile 128x64, BK=32, bank-conflict swizzle:
// chunk c (8 elems) of row r is stored at LDS slot (c+r)&3.
// ---------------------------------------------------------------------------
__global__ __launch_bounds__(256) void gemm1_split(
    const u16* __restrict__ Ahi, const u16* __restrict__ Alo,
    const u16* __restrict__ Bhi, const u16* __restrict__ Blo,
    const float* __restrict__ bias, float* __restrict__ Cout)
{
  const int r0 = blockIdx.y * 128, n0 = blockIdx.x * 64;
  __shared__ __align__(16) u16 Ah[128 * 32], Al[128 * 32];
  __shared__ __align__(16) u16 Bh[64 * 32],  Bl[64 * 32];

  const int tid = threadIdx.x;
  const int wave = tid >> 6, lane = tid & 63;
  const int srow = lane >> 2;            // 0..15 (16 rows per GLL16 at BK=32)
  const int slot = lane & 3;             // 16B slot in LDS row

  const u16 *ahp[2], *alp[2]; u16 *ahd[2], *aldd[2];
#pragma unroll
  for (int s = 0; s < 2; s++) {
    int row = wave * 32 + s * 16 + srow;
    int c = (slot - row) & 3;            // swizzled source chunk
    size_t g = (size_t)(r0 + row) * DIM + c * 8;
    ahp[s] = Ahi + g; alp[s] = Alo + g;
    ahd[s] = &Ah[(wave * 32 + s * 16) * 32];
    aldd[s] = &Al[(wave * 32 + s * 16) * 32];
  }
  int brow = wave * 16 + srow;
  int cb = (slot - brow) & 3;
  const u16* bhp = Bhi + (size_t)(n0 + brow) * DIM + cb * 8;
  const u16* blp = Blo + (size_t)(n0 + brow) * DIM + cb * 8;
  u16* bhd = &Bh[(wave * 16) * 32];
  u16* bld = &Bl[(wave * 16) * 32];

  f32x4 zero = {0.f, 0.f, 0.f, 0.f};
  f32x4 acc[4][2];
#pragma unroll
  for (int a = 0; a < 4; a++)
#pragma unroll
    for (int b = 0; b < 2; b++) acc[a][b] = zero;

  const int quad = lane >> 4, l16 = lane & 15;
  const int wm = (wave & 1) * 64, wn = (wave >> 1) * 32;

  for (int k0 = 0; k0 < DIM; k0 += 32) {
#pragma unroll
    for (int s = 0; s < 2; s++) {
      GLL16(ahp[s] + k0, ahd[s]);
      GLL16(alp[s] + k0, aldd[s]);
    }
    GLL16(bhp + k0, bhd);
    GLL16(blp + k0, bld);
    __syncthreads();
    bf16x8 ah[4], al[4], bh[2], bl[2];
#pragma unroll
    for (int mt = 0; mt < 4; mt++) {
      int R = wm + mt * 16 + l16;
      int off = R * 32 + ((quad + R) & 3) * 8;
      ah[mt] = *(const bf16x8*)&Ah[off];
      al[mt] = *(const bf16x8*)&Al[off];
    }
#pragma unroll
    for (int nt = 0; nt < 2; nt++) {
      int R = wn + nt * 16 + l16;
      int off = R * 32 + ((quad + R) & 3) * 8;
      bh[nt] = *(const bf16x8*)&Bh[off];
      bl[nt] = *(const bf16x8*)&Bl[off];
    }
#pragma unroll
    for (int mt = 0; mt < 4; mt++)
#pragma unroll
      for (int nt = 0; nt < 2; nt++) {
        acc[mt][nt] = __builtin_amdgcn_mfma_f32_16x16x32_bf16(ah[mt], bh[nt], acc[mt][nt], 0, 0, 0);
        acc[mt][nt] = __builtin_amdgcn_mfma_f32_16x16x32_bf16(ah[mt], bl[nt], acc[mt][nt], 0, 0, 0);
        acc[mt][nt] = __builtin_amdgcn_mfma_f32_16x16x32_bf16(al[mt], bh[nt], acc[mt][nt], 0, 0, 0);
      }
    __syncthreads();
  }

  float bv[2];
#pragma unroll
  for (int nt = 0; nt < 2; nt++) bv[nt] = bias[n0 + wn + nt * 16 + l16];

#pragma unroll
  for (int mt = 0; mt < 4; mt++)
#pragma unroll
    for (int reg = 0; reg < 4; reg++) {
      int r = wm + mt * 16 + quad * 4 + reg;
      size_t crow = (size_t)(r0 + r) * DIM;
#pragma unroll
      for (int nt = 0; nt < 2; nt++) {
        int c = n0 + wn + nt * 16 + l16;
        Cout[crow + c] = gelu_fast(acc[mt][nt][reg] + bv[nt]);
      }
    }
}

// ---------------------------------------------------------------------------
// Expert GEMM, compact live-block map. Tile 128x128, BK=64, swizzled LDS:
// chunk c (16B) of row r stored at slot (c+r)&7 -> conflict-free frag reads.
// EPI 0: bias+GELU -> bf16.  EPI 1: bias -> bf16.
// ---------------------------------------------------------------------------
template<int EPI, bool GATHER>
__global__ __launch_bounds__(256) void gemm_bt(
    const u16* __restrict__ A, const u16* __restrict__ BT,
    const float* __restrict__ bias,
    const int* __restrict__ counts, const int* __restrict__ offs,
    const int* __restrict__ map_e, const int* __restrict__ map_r0,
    const int* __restrict__ tok,
    u16* __restrict__ Cout, int N, int K)
{
  const int mb = blockIdx.y;
  const int e  = map_e[mb];
  if (e < 0) return;                                  // pad block
  const int cnt  = counts[e];
  const int r0   = map_r0[mb];
  const int base = offs[e];
  const int n0   = blockIdx.x * 128;
  const u16* BTe = BT + (size_t)e * N * K;
  const float* be = bias + (size_t)e * N;

  __shared__ __align__(16) u16 As[128 * 64];
  __shared__ __align__(16) u16 Bs[128 * 64];

  const int tid = threadIdx.x;
  const int wave = tid >> 6, lane = tid & 63;
  const int srow = lane >> 3;             // 0..7 (8 rows per GLL16 at BK=64)
  const int slot = lane & 7;              // 16B slot in LDS row

  const u16 *agp[4], *bgp[4];
  u16 *ald[4], *bld[4];
#pragma unroll
  for (int s = 0; s < 4; s++) {
    int row = wave * 32 + s * 8 + srow;               // 0..127
    int c = (slot - row) & 7;                         // swizzled source chunk
    int rr = min(r0 + row, cnt - 1);                  // clamp tail (stores masked)
    int arow = GATHER ? tok[base + rr] : (base + rr);
    agp[s] = A + (size_t)arow * K + c * 8;
    ald[s] = &As[(wave * 32 + s * 8) * 64];           // wave-uniform LDS base
    int nr = n0 + row;
    bgp[s] = BTe + (size_t)nr * K + c * 8;
    bld[s] = &Bs[(wave * 32 + s * 8) * 64];
  }

  f32x4 zero = {0.f, 0.f, 0.f, 0.f};
  f32x4 acc[4][4];
#pragma unroll
  for (int a = 0; a < 4; a++)
#pragma unroll
    for (int b = 0; b < 4; b++) acc[a][b] = zero;

  const int quad = lane >> 4, l16 = lane & 15;
  const int wm = (wave & 1) * 64, wn = (wave >> 1) * 64;

  for (int k0 = 0; k0 < K; k0 += 64) {
#pragma unroll
    for (int s = 0; s < 4; s++) {
      GLL16(agp[s] + k0, ald[s]);
      GLL16(bgp[s] + k0, bld[s]);
    }
    __syncthreads();
#pragma unroll
    for (int kk = 0; kk < 2; kk++) {
      bf16x8 af[4], bfv[4];
#pragma unroll
      for (int mt = 0; mt < 4; mt++) {
        int R = wm + mt * 16 + l16;
        af[mt] = *(const bf16x8*)&As[R * 64 + ((kk * 4 + quad + R) & 7) * 8];
      }
#pragma unroll
      for (int nt = 0; nt < 4; nt++) {
        int R = wn + nt * 16 + l16;
        bfv[nt] = *(const bf16x8*)&Bs[R * 64 + ((kk * 4 + quad + R) & 7) * 8];
      }
#pragma unroll
      for (int mt = 0; mt < 4; mt++)
#pragma unroll
        for (int nt = 0; nt < 4; nt++)
          acc[mt][nt] = __builtin_amdgcn_mfma_f32_16x16x32_bf16(
              af[mt], bfv[nt], acc[mt][nt], 0, 0, 0);
    }
    __syncthreads();
  }

  float bv[4];
#pragma unroll
  for (int nt = 0; nt < 4; nt++) bv[nt] = be[n0 + wn + nt * 16 + l16];

#pragma unroll
  for (int mt = 0; mt < 4; mt++)
#pragma unroll
    for (int reg = 0; reg < 4; reg++) {
      int r = wm + mt * 16 + quad * 4 + reg;         // C/D: row=quad*4+reg, col=lane&15
      if (r0 + r < cnt) {
        size_t crow = (size_t)(base + r0 + r) * N;
#pragma unroll
        for (int nt = 0; nt < 4; nt++) {
          int c = n0 + wn + nt * 16 + l16;
          float v = acc[mt][nt][reg] + bv[nt];
          Cout[crow + c] = f2bf(EPI == 0 ? gelu_fast(v) : v);
        }
      }
    }
}

// ---------------------------------------------------------------------------
// Router stage 2a: logits = hr(fp32) @ Wr2 + br2; flag near-ties (2nd vs 3rd)
// ---------------------------------------------------------------------------
__global__ __launch_bounds__(256) void router2a(
    const float* __restrict__ hr, const float* __restrict__ Wr2,
    const float* __restrict__ br2,
    float* __restrict__ logits, int* __restrict__ nflag, int* __restrict__ flaglist)
{
  __shared__ float w[NEXP * DIM];
  __shared__ float bsh[NEXP];
  const int tid = threadIdx.x;
  for (int i = tid; i < NEXP * DIM; i += 256) {
    int d = i >> 3, e2 = i & 7;
    w[e2 * DIM + d] = Wr2[i];
  }
  if (tid < NEXP) bsh[tid] = br2[tid];
  __syncthreads();
  const int wave = tid >> 6, lane = tid & 63;
  for (int tt = 0; tt < 4; tt++) {
    int t = blockIdx.x * 16 + wave * 4 + tt;
    float acc[NEXP] = {0, 0, 0, 0, 0, 0, 0, 0};
    for (int jj = 0; jj < 16; jj++) {
      int d = jj * 64 + lane;
      float hv = hr[(size_t)t * DIM + d];
#pragma unroll
      for (int e2 = 0; e2 < NEXP; e2++) acc[e2] += hv * w[e2 * DIM + d];
    }
#pragma unroll
    for (int off = 32; off > 0; off >>= 1)
#pragma unroll
      for (int e2 = 0; e2 < NEXP; e2++) acc[e2] += __shfl_xor(acc[e2], off, 64);
    if (lane == 0) {
      float l[NEXP];
#pragma unroll
      for (int e2 = 0; e2 < NEXP; e2++) {
        l[e2] = acc[e2] + bsh[e2];
        logits[(size_t)t * NEXP + e2] = l[e2];
      }
      int e0 = 0;
#pragma unroll
      for (int e2 = 1; e2 < NEXP; e2++) if (l[e2] > l[e0]) e0 = e2;
      int e1 = (e0 == 0) ? 1 : 0;
#pragma unroll
      for (int e2 = 0; e2 < NEXP; e2++) if (e2 != e0 && l[e2] > l[e1]) e1 = e2;
      float third = -1e30f;
#pragma unroll
      for (int e2 = 0; e2 < NEXP; e2++)
        if (e2 != e0 && e2 != e1 && l[e2] > third) third = l[e2];
      if (l[e1] - third < FLAG_GAP) {
        int idx = atomicAdd(nflag, 1);
        if (idx < MAXFLAG) flaglist[idx] = t;
      }
    }
  }
}

// ---------------------------------------------------------------------------
// fp64 exact recompute of one flagged token's logits. K split over 4 waves
// (pipelined independent loads), LDS partials, block reduction.
// ---------------------------------------------------------------------------
__global__ __launch_bounds__(256) void fixup_fp64(
    const float* __restrict__ x, const float* __restrict__ Wr1,
    const float* __restrict__ br1, const float* __restrict__ Wr2,
    const float* __restrict__ br2,
    const int* __restrict__ nflag, const int* __restrict__ flaglist,
    float* __restrict__ logits)
{
  int nf = *nflag; if (nf > MAXFLAG) nf = MAXFLAG;
  if ((int)blockIdx.x >= nf) return;
  const int t = flaglist[blockIdx.x];
  __shared__ float xs[DIM];
  __shared__ double hpart[4][DIM];     // 32 KB
  const int tid = threadIdx.x, wave = tid >> 6, lane = tid & 63;
  for (int i = tid; i < DIM; i += 256) xs[i] = x[(size_t)t * DIM + i];
  __syncthreads();
  double h[4][4] = {};
  for (int ki = 0; ki < 256; ki++) {
    int k = wave * 256 + ki;
    double xv = (double)xs[k];
#pragma unroll
    for (int g = 0; g < 4; g++) {
      f32x4 wv = *(const f32x4*)&Wr1[(size_t)k * DIM + g * 256 + lane * 4];
#pragma unroll
      for (int j = 0; j < 4; j++) h[g][j] = fma(xv, (double)wv[j], h[g][j]);
    }
  }
#pragma unroll
  for (int g = 0; g < 4; g++)
#pragma unroll
    for (int j = 0; j < 4; j++) hpart[wave][g * 256 + lane * 4 + j] = h[g][j];
  __syncthreads();
  double lacc[NEXP] = {0, 0, 0, 0, 0, 0, 0, 0};
#pragma unroll
  for (int j = 0; j < 4; j++) {
    int d = tid * 4 + j;
    double v = hpart[0][d] + hpart[1][d] + hpart[2][d] + hpart[3][d] + (double)br1[d];
    v = 0.5 * v * (1.0 + erf(v * 0.70710678118654752440));  // exact GELU
#pragma unroll
    for (int e2 = 0; e2 < NEXP; e2++)
      lacc[e2] = fma(v, (double)Wr2[(size_t)d * NEXP + e2], lacc[e2]);
  }
  __syncthreads();                      // all reads of hpart done
  double* red = &hpart[0][0];           // reuse as [256][8] scratch
#pragma unroll
  for (int e2 = 0; e2 < NEXP; e2++) red[tid * NEXP + e2] = lacc[e2];
  __syncthreads();
  if (tid < NEXP) {
    double s = (double)br2[tid];
    for (int i = 0; i < 256; i++) s += red[i * NEXP + tid];
    logits[(size_t)t * NEXP + tid] = (float)s;
  }
}

// ---------------------------------------------------------------------------
// finalize: top-2 + renormalized gates + expert ids + per-expert counts
// ---------------------------------------------------------------------------
__global__ __launch_bounds__(256) void finalize_route(
    const float* __restrict__ logits, float2* __restrict__ gates,
    int* __restrict__ experts, int* __restrict__ counts)
{
  __shared__ int lc[NEXP];
  const int tid = threadIdx.x;
  if (tid < NEXP) lc[tid] = 0;
  __syncthreads();
  const int t = blockIdx.x * 256 + tid;
  float l[NEXP];
#pragma unroll
  for (int e2 = 0; e2 < NEXP; e2++) l[e2] = logits[(size_t)t * NEXP + e2];
  int e0 = 0;
#pragma unroll
  for (int e2 = 1; e2 < NEXP; e2++) if (l[e2] > l[e0]) e0 = e2;  // ties: low idx
  int e1 = (e0 == 0) ? 1 : 0;
#pragma unroll
  for (int e2 = 0; e2 < NEXP; e2++) if (e2 != e0 && l[e2] > l[e1]) e1 = e2;
  float p1 = expf(l[e1] - l[e0]);
  float s = 1.0f + p1;
  gates[t] = make_float2(1.0f / s, p1 / s);
  experts[2 * t]     = e0;
  experts[2 * t + 1] = e1;
  atomicAdd(&lc[e0], 1); atomicAdd(&lc[e1], 1);
  __syncthreads();
  if (tid < NEXP && lc[tid]) atomicAdd(&counts[tid], lc[tid]);
}

__global__ void zero_meta(int* meta) {
  if (threadIdx.x < 32) meta[threadIdx.x] = 0;
}

// offsets/cursors + compact live-block map (sum(counts)=NSLOT => <=135 blocks)
__global__ void prefix8(const int* __restrict__ counts, int* __restrict__ offs,
                        int* __restrict__ cursor,
                        int* __restrict__ map_e, int* __restrict__ map_r0) {
  if (threadIdx.x == 0) {
    int a = 0, m = 0;
    for (int e = 0; e < NEXP; e++) {
      offs[e] = a; cursor[e] = a;
      int nb = (counts[e] + 127) >> 7;
      for (int j = 0; j < nb; j++) { map_e[m] = e; map_r0[m] = j << 7; m++; }
      a += counts[e];
    }
    for (; m < MBLK; m++) { map_e[m] = -1; map_r0[m] = 0; }
  }
}

__global__ __launch_bounds__(256) void scatter_tok(
    const int* __restrict__ experts, int* __restrict__ cursor,
    int* __restrict__ tok_of_slot, int* __restrict__ slot_of_token)
{
  int idx = blockIdx.x * 256 + threadIdx.x;  // over NSLOT
  int e = experts[idx];
  int slot = atomicAdd(&cursor[e], 1);
  tok_of_slot[slot] = idx >> 1;
  slot_of_token[idx] = slot;
}

// out[t] = g0*y[slot0] + g1*y[slot1]  (y bf16; b2 added in layer-2 epilogue)
__global__ __launch_bounds__(256) void combine(
    const u16* __restrict__ y, const float2* __restrict__ gates,
    const int* __restrict__ slot_of_token, float* __restrict__ out)
{
  int t = blockIdx.x, tid = threadIdx.x;
  int s0 = slot_of_token[2 * t], s1 = slot_of_token[2 * t + 1];
  float2 g = gates[t];
  u16x4 a = *(const u16x4*)&y[(size_t)s0 * DIM + tid * 4];
  u16x4 b = *(const u16x4*)&y[(size_t)s1 * DIM + tid * 4];
  f32x4 o;
#pragma unroll
  for (int j = 0; j < 4; j++) o[j] = g.x * bf2f(a[j]) + g.y * bf2f(b[j]);
  *(f32x4*)&out[(size_t)t * DIM + tid * 4] = o;
}

// ---------------------------------------------------------------------------
extern "C" void kernel_launch(void* const* d_in, const int* in_sizes, int n_in,
                              void* d_out, int out_size, void* d_ws, size_t ws_size,
                              hipStream_t stream)
{
  const float* x   = (const float*)d_in[0];  // [T,D] fp32
  const float* Wr1 = (const float*)d_in[1];  // [D,D]
  const float* br1 = (const float*)d_in[2];  // [D]
  const float* Wr2 = (const float*)d_in[3];  // [D,E]
  const float* br2 = (const float*)d_in[4];  // [E]
  const float* W1  = (const float*)d_in[5];  // [E,D,H]
  const float* b1  = (const float*)d_in[6];  // [E,H]
  const float* W2  = (const float*)d_in[7];  // [E,H,D]
  const float* b2  = (const float*)d_in[8];  // [E,D]
  float* out = (float*)d_out;

  char* ws = (char*)d_ws;
  const size_t MB = 1024 * 1024;
  // explicit layout with lifetime-based aliasing (~294 MB total):
  u16*   xhi    = (u16*)  (ws + 0 * MB);     // [0,16)   dead after expert-L1
  u16*   xlo    = (u16*)  (ws + 16 * MB);    // [16,32)  dead after gemm1
  u16*   Wr1Thi = (u16*)  (ws + 32 * MB);    // [32,34)  dead after gemm1
  u16*   Wr1Tlo = (u16*)  (ws + 34 * MB);    // [34,36)  dead after gemm1
  u16*   W1T    = (u16*)  (ws + 36 * MB);    // [36,100) dead after expert-L1
  u16*   W2T    = (u16*)  (ws + 100 * MB);   // [100,164) live until L2
  u16*   hidden = (u16*)  (ws + 164 * MB);   // [164,292) bf16
  float* hr32   = (float*)(ws + 164 * MB);   // alias: dead before L1 writes hidden
  u16*   y      = (u16*)  (ws + 0 * MB);     // [0,32) bf16: written by L2, after
                                             //   xhi/xlo are dead
  char* tail = ws + 292 * MB;
  float*  logits = (float*)tail;                      tail += (size_t)T_TOK * NEXP * 4;
  float2* gates  = (float2*)tail;                     tail += (size_t)T_TOK * 8;
  int* experts       = (int*)tail;                    tail += (size_t)NSLOT * 4;
  int* tok_of_slot   = (int*)tail;                    tail += (size_t)NSLOT * 4;
  int* slot_of_token = (int*)tail;                    tail += (size_t)NSLOT * 4;
  int* flaglist      = (int*)tail;                    tail += (size_t)MAXFLAG * 4;
  int* map_e         = (int*)tail;                    tail += (size_t)MBLK * 4;
  int* map_r0        = (int*)tail;                    tail += (size_t)MBLK * 4;
  int* meta          = (int*)tail;  // counts[8] | offs[8] | cursor[8] | nflag
  int* counts = meta, *offs = meta + 8, *cursor = meta + 16, *nflag = meta + 24;

  zero_meta<<<1, 64, 0, stream>>>(meta);
  // ingest: x -> bf16 hi/lo split; weights -> bf16 B^T (Wr1 also split)
  split_cast<<<T_TOK * DIM / 1024, 256, 0, stream>>>(x, xhi, xlo, T_TOK * DIM / 4);
  transpose_cast_split<<<dim3(16, 16, 1), 256, 0, stream>>>(Wr1, Wr1Thi, Wr1Tlo, DIM, DIM);
  transpose_cast<<<dim3(64, 16, NEXP), 256, 0, stream>>>(W1, W1T, DIM, HID);
  transpose_cast<<<dim3(16, 64, NEXP), 256, 0, stream>>>(W2, W2T, HID, DIM);
  // router layer 1, fp32-class precision via 3-product split-bf16 MFMA
  gemm1_split<<<dim3(DIM / 64, T_TOK / 128), 256, 0, stream>>>(
      xhi, xlo, Wr1Thi, Wr1Tlo, br1, hr32);
  // fp32 logits + near-tie flags; fp64 fixup; final top-2 + gates + counts
  router2a<<<T_TOK / 16, 256, 0, stream>>>(hr32, Wr2, br2, logits, nflag, flaglist);
  fixup_fp64<<<MAXFLAG, 256, 0, stream>>>(x, Wr1, br1, Wr2, br2, nflag, flaglist, logits);
  finalize_route<<<T_TOK / 256, 256, 0, stream>>>(logits, gates, experts, counts);
  prefix8<<<1, 64, 0, stream>>>(counts, offs, cursor, map_e, map_r0);
  scatter_tok<<<NSLOT / 256, 256, 0, stream>>>(experts, cursor,
                                               tok_of_slot, slot_of_token);
  // expert layer 1 (gather x rows): hidden = gelu(xg @ W1[e] + b1[e]) bf16
  gemm_bt<0, true><<<dim3(HID / 128, MBLK), 256, 0, stream>>>(
      xhi, W1T, b1, counts, offs, map_e, map_r0, tok_of_slot, hidden, HID, DIM);
  // expert layer 2: y = hidden @ W2[e] + b2[e], bf16
  gemm_bt<1, false><<<dim3(DIM / 128, MBLK), 256, 0, stream>>>(
      hidden, W2T, b2, counts, offs, map_e, map_r0, nullptr, y, DIM, HID);
  // weighted combine -> fp32 out
  combine<<<T_TOK, 256, 0, stream>>>(y, gates, slot_of_token, out);
}